// Round 1
// 246.513 us; speedup vs baseline: 1.0322x; 1.0322x over previous
//
#include <hip/hip_runtime.h>

#define NN 4096
#define FF 128
#define EE 64

typedef unsigned short u16;
typedef unsigned long long u64;
typedef float vf4 __attribute__((ext_vector_type(4)));

__device__ __forceinline__ float lrelu(float x) { return x > 0.f ? x : 0.2f * x; }

// K0: fused pre-pass, two block kinds in ONE dispatch (they are independent):
//  blocks 0..63   : compute v6 (W_d @ a_d, redundantly per block into LDS) then
//                   s1/p for 64 nodes each. Blocks 0..15 also zero CSC counters.
//  blocks 64..319 : old k_feat (u = t@W.T, out rows 0..63) for 16 nodes each.
// k_feat never consumed v6 outputs except for s1/p — those now live in the
// producer blocks, so k_scan depends ONLY on this kernel and the chain is
// 4 dispatches instead of 5.
__global__ __launch_bounds__(256)
void k_pre(const float* __restrict__ t, const float* __restrict__ weight,
           const float* __restrict__ Wf, const float* __restrict__ af1, const float* __restrict__ af2,
           const float* __restrict__ Wb, const float* __restrict__ ab1, const float* __restrict__ ab2,
           const float* __restrict__ Wg, const float* __restrict__ ag1, const float* __restrict__ ag2,
           float* __restrict__ u, float* __restrict__ s1, float* __restrict__ p,
           float* __restrict__ out, int* __restrict__ ccnt)
{
    __shared__ float ww[64 * 129];   // weight[e][q] at e*129+q  (129: bank-spread)
    __shared__ float tt[16 * 130];   // t[node][q] at node*130+q
    __shared__ float uacc[64 * 17];  // u[e][node] staging for transposed out write
    __shared__ float w6[6 * FF];     // v6 for the producer blocks
    int b = blockIdx.x, tid = threadIdx.x;

    if (b < 64) {
        // ---------- producer blocks: v6 -> s1/p ----------
        if (b < 16) ccnt[b * 256 + tid] = 0;
        const float* Ws[3]  = {Wf, Wb, Wg};
        const float* a1s[3] = {af1, ab1, ag1};
        const float* a2s[3] = {af2, ab2, ag2};
        for (int idx = tid; idx < 768; idx += 256) {
            int vi = idx >> 7, f = idx & 127, dd = vi >> 1;
            const float4* a4 = reinterpret_cast<const float4*>((vi & 1) ? a2s[dd] : a1s[dd]);
            const float4* W4 = reinterpret_cast<const float4*>(Ws[dd] + (size_t)f * EE);
            float s = 0.f;
            #pragma unroll
            for (int e4 = 0; e4 < 16; ++e4) {
                float4 wv = W4[e4], av = a4[e4];
                s += wv.x * av.x + wv.y * av.y + wv.z * av.z + wv.w * av.w;
            }
            w6[vi * FF + f] = s;
        }
        __syncthreads();
        int nb = b * 64;
        for (int idx = tid; idx < 384; idx += 256) {
            int n = idx & 63, vi = idx >> 6;      // vi uniform per wave -> w6 broadcast reads
            const float4* t4 = reinterpret_cast<const float4*>(t + (size_t)(nb + n) * FF);
            const float* wv = &w6[vi * FF];
            float s = 0.f;
            #pragma unroll 8
            for (int q4 = 0; q4 < 32; ++q4) {
                float4 v = t4[q4];
                s += v.x * wv[q4 * 4] + v.y * wv[q4 * 4 + 1]
                   + v.z * wv[q4 * 4 + 2] + v.w * wv[q4 * 4 + 3];
            }
            int dd = vi >> 1;
            if (vi & 1) p[dd * NN + nb + n] = s; else s1[dd * NN + nb + n] = s;
        }
        return;
    }

    // ---------- feat blocks: u + out rows 0..63 ----------
    int n0 = (b - 64) * 16;
    const float4* w4 = reinterpret_cast<const float4*>(weight);
    for (int i = tid; i < 2048; i += 256) {
        float4 v = w4[i];
        int fi = i * 4, e = fi >> 7, q = fi & 127;
        float* dst = &ww[e * 129 + q];
        dst[0] = v.x; dst[1] = v.y; dst[2] = v.z; dst[3] = v.w;
    }
    const float4* t4 = reinterpret_cast<const float4*>(t + (size_t)n0 * FF);
    for (int i = tid; i < 512; i += 256) {
        float4 v = t4[i];
        int fi = i * 4, nd = fi >> 7, q = fi & 127;
        float* dst = &tt[nd * 130 + q];
        dst[0] = v.x; dst[1] = v.y; dst[2] = v.z; dst[3] = v.w;
    }
    __syncthreads();
    int g = tid >> 6, lane = tid & 63;
    for (int k = 0; k < 4; ++k) {
        int nd = g * 4 + k;
        const float* trow = &tt[nd * 130];
        const float* wrow = &ww[lane * 129];
        float acc = 0.f;
        #pragma unroll 16
        for (int q = 0; q < 128; ++q) acc += wrow[q] * trow[q];
        u[(size_t)(n0 + nd) * EE + lane] = acc;
        uacc[lane * 17 + nd] = acc;
    }
    __syncthreads();
    int e = tid >> 2, io = (tid & 3) * 4;
    float* orow = out + (size_t)e * NN + n0 + io;
    orow[0] = uacc[e * 17 + io];
    orow[1] = uacc[e * 17 + io + 1];
    orow[2] = uacc[e * 17 + io + 2];
    orow[3] = uacc[e * 17 + io + 3];
}

// K1: streaming scan, NON-TEMPORAL adjacency loads (R16/R18-proven). ONE WAVE =
// ONE ROW. NEW: direction-interleaved schedule (d = gl % 3) so atomic-heavy
// backward waves are mixed uniformly with pure-streaming fwd/geo waves instead
// of forming a clustered middle phase. Outputs keep the logical gr = d*NN + r
// layout, so all consumers are unchanged.
__global__ __launch_bounds__(256, 8)
void k_scan(const float* __restrict__ Af, const float* __restrict__ Ab, const float* __restrict__ Ag,
            const float* __restrict__ p,
            u16* __restrict__ csr, int* __restrict__ cnt, float* __restrict__ s2,
            u16* __restrict__ csc, int* __restrict__ ccnt, int stride)
{
    int wid = threadIdx.x >> 6, lane = threadIdx.x & 63;
    int gl = blockIdx.x * 4 + wid;             // 0 .. 3*NN-1 (schedule index)
    int d = gl % 3, r = gl / 3;
    int gr = d * NN + r;                       // logical row id (consumer layout)
    const float* A = d == 0 ? Af : (d == 1 ? Ab : Ag);
    const vf4* row4 = reinterpret_cast<const vf4*>(A + (size_t)r * NN);
    const float* pd = p + d * NN;

    u64 mask = 0ull;
    #pragma unroll
    for (int j = 0; j < 16; ++j) {
        vf4 L = __builtin_nontemporal_load(row4 + j * 64 + lane);
        unsigned mm = (L.x != 0.f ? 1u : 0u) | (L.y != 0.f ? 2u : 0u) |
                      (L.z != 0.f ? 4u : 0u) | (L.w != 0.f ? 8u : 0u);
        mask |= ((u64)mm) << (j * 4);
    }

    int lc = __popcll(mask);
    int sc = lc;
    for (int off = 1; off < 64; off <<= 1) {
        int o = __shfl_up(sc, off);
        if (lane >= off) sc += o;
    }
    int total = __shfl(sc, 63);
    int pos = sc - lc;
    u16* crow = csr + (size_t)gr * stride;
    float q = 0.f;
    u64 m = mask;
    while (m) {
        int bb = __ffsll(m) - 1;
        m &= m - 1;
        int col = ((bb >> 2) << 8) + (lane << 2) + (bb & 3);
        if (pos < stride) crow[pos] = (u16)col;
        pos++;
        q += pd[col];
        if (d == 1) {
            int cp = atomicAdd(&ccnt[col], 1);
            if (cp < stride) csc[(size_t)col * stride + cp] = (u16)r;
        }
    }
    for (int off = 32; off; off >>= 1) q += __shfl_xor(q, off);
    if (lane == 0) {
        cnt[gr] = total;
        s2[gr] = q / fmaxf((float)total, 1.f);
    }
}

// K2: backward row denominators Zb[j] = sum_{col} exp(lrelu(s1b[j]+s2b[col]))
__global__ void k_zb(const float* __restrict__ s1, const float* __restrict__ s2,
                     const u16* __restrict__ csr, const int* __restrict__ cnt, int stride,
                     float* __restrict__ Zb)
{
    int tid = threadIdx.x, wave = tid >> 6, lane = tid & 63;
    int j = blockIdx.x * 4 + wave;
    int gr = NN + j;
    int nnz = min(cnt[gr], stride);
    const u16* crow = csr + (size_t)gr * stride;
    float s1j = s1[gr];
    const float* s2b = s2 + NN;
    float z = 0.f;
    if (lane < nnz)      z += __expf(lrelu(s1j + s2b[crow[lane]]));
    if (lane + 64 < nnz) z += __expf(lrelu(s1j + s2b[crow[lane + 64]]));
    for (int off = 32; off; off >>= 1) z += __shfl_xor(z, off);
    if (lane == 0) Zb[j] = z;
}

// K3: unified consumer. NEW: gather loop widened to ILP-4 (4 independent 256-B
// u-row loads in flight per wave instead of 2 — L2-latency pipelining).
__global__ __launch_bounds__(256)
void k_out(const float* __restrict__ u,
           const float* __restrict__ s1, const float* __restrict__ s2,
           const float* __restrict__ Zb,
           const u16* __restrict__ csr, const int* __restrict__ cnt,
           const u16* __restrict__ csc, const int* __restrict__ ccnt, int stride,
           float* __restrict__ out)
{
    __shared__ float oacc[16 * 66];
    int gr0 = blockIdx.x * 16;
    int d = gr0 >> 12, i0 = gr0 & (NN - 1);
    int wid = threadIdx.x >> 6, lane = threadIdx.x & 63;
    for (int k = 0; k < 4; ++k) {
        int lr = k * 4 + wid;
        int i = i0 + lr;
        int gr = gr0 + lr;
        int nnz;
        int c0v = 0, c1v = 0;
        float w0v = 0.f, w1v = 0.f;
        if (d == 1) {
            nnz = min(ccnt[i], stride);
            const u16* cc = csc + (size_t)i * stride;
            float s2i = s2[NN + i];
            if (lane < nnz)      { int j = cc[lane];      c0v = j; w0v = __expf(lrelu(s1[NN + j] + s2i)) / Zb[j]; }
            if (lane + 64 < nnz) { int j = cc[lane + 64]; c1v = j; w1v = __expf(lrelu(s1[NN + j] + s2i)) / Zb[j]; }
        } else {
            nnz = min(cnt[gr], stride);
            const u16* crow = csr + (size_t)gr * stride;
            float s1i = s1[gr];
            const float* s2d = s2 + d * NN;
            float z = 0.f;
            if (lane < nnz)      { int c = crow[lane];      c0v = c; w0v = __expf(lrelu(s1i + s2d[c])); z += w0v; }
            if (lane + 64 < nnz) { int c = crow[lane + 64]; c1v = c; w1v = __expf(lrelu(s1i + s2d[c])); z += w1v; }
            for (int off = 32; off; off >>= 1) z += __shfl_xor(z, off);
            float invz = z > 0.f ? 1.f / z : 0.f;
            w0v *= invz; w1v *= invz;
        }
        float a0 = 0.f, a1 = 0.f, a2 = 0.f, a3 = 0.f;
        int n0c = nnz < 64 ? nnz : 64;
        int kk = 0;
        for (; kk + 3 < n0c; kk += 4) {
            int ca = __shfl(c0v, kk),     cb = __shfl(c0v, kk + 1);
            int cc2 = __shfl(c0v, kk + 2), cd = __shfl(c0v, kk + 3);
            float wa = __shfl(w0v, kk),     wb = __shfl(w0v, kk + 1);
            float wc = __shfl(w0v, kk + 2), wd = __shfl(w0v, kk + 3);
            a0 += wa * u[(size_t)ca  * EE + lane];
            a1 += wb * u[(size_t)cb  * EE + lane];
            a2 += wc * u[(size_t)cc2 * EE + lane];
            a3 += wd * u[(size_t)cd  * EE + lane];
        }
        for (; kk < n0c; ++kk)
            a0 += __shfl(w0v, kk) * u[(size_t)__shfl(c0v, kk) * EE + lane];
        int n1c = nnz - 64;
        kk = 0;
        for (; kk + 3 < n1c; kk += 4) {
            int ca = __shfl(c1v, kk),     cb = __shfl(c1v, kk + 1);
            int cc2 = __shfl(c1v, kk + 2), cd = __shfl(c1v, kk + 3);
            float wa = __shfl(w1v, kk),     wb = __shfl(w1v, kk + 1);
            float wc = __shfl(w1v, kk + 2), wd = __shfl(w1v, kk + 3);
            a0 += wa * u[(size_t)ca  * EE + lane];
            a1 += wb * u[(size_t)cb  * EE + lane];
            a2 += wc * u[(size_t)cc2 * EE + lane];
            a3 += wd * u[(size_t)cd  * EE + lane];
        }
        for (; kk < n1c; ++kk)
            a0 += __shfl(w1v, kk) * u[(size_t)__shfl(c1v, kk) * EE + lane];
        oacc[lr * 66 + lane] = (a0 + a1) + (a2 + a3);
    }
    __syncthreads();
    int e = threadIdx.x >> 2, io = (threadIdx.x & 3) * 4;
    int base = 64 + (d << 6);
    float* orow = out + (size_t)(base + e) * NN + i0 + io;
    orow[0] = oacc[(io    ) * 66 + e];
    orow[1] = oacc[(io + 1) * 66 + e];
    orow[2] = oacc[(io + 2) * 66 + e];
    orow[3] = oacc[(io + 3) * 66 + e];
}

extern "C" void kernel_launch(void* const* d_in, const int* in_sizes, int n_in,
                              void* d_out, int out_size, void* d_ws, size_t ws_size,
                              hipStream_t stream)
{
    const float* t   = (const float*)d_in[0];
    const float* Ag  = (const float*)d_in[1];
    const float* Af  = (const float*)d_in[2];
    const float* Ab  = (const float*)d_in[3];
    const float* W   = (const float*)d_in[4];
    const float* Wf  = (const float*)d_in[5];
    const float* af1 = (const float*)d_in[6];
    const float* af2 = (const float*)d_in[7];
    const float* Wb  = (const float*)d_in[8];
    const float* ab1 = (const float*)d_in[9];
    const float* ab2 = (const float*)d_in[10];
    const float* Wg  = (const float*)d_in[11];
    const float* ag1 = (const float*)d_in[12];
    const float* ag2 = (const float*)d_in[13];
    float* out = (float*)d_out;

    float* ws = (float*)d_ws;
    float* v6  = ws;                              // 768 (unused slot kept for layout stability)
    float* s1  = v6 + 6 * FF;                     // 3N
    float* p   = s1 + 3 * NN;                     // 3N
    float* s2  = p + 3 * NN;                      // 3N
    float* Zb  = s2 + 3 * NN;                     // N
    float* u   = Zb + NN;                         // N*E
    int*   cnt  = (int*)(u + (size_t)NN * EE);    // 3N
    int*   ccnt = cnt + 3 * NN;                   // N
    u16*   csr  = (u16*)(ccnt + NN);              // 3N*stride
    // csc follows csr: N*stride

    size_t base_bytes = ((char*)csr) - ((char*)d_ws);
    int stride = 128;
    if (base_bytes + (size_t)4 * NN * 128 * 2 > ws_size) stride = 96;
    if (base_bytes + (size_t)4 * NN * 96 * 2 > ws_size)  stride = 64;
    u16* csc = csr + (size_t)3 * NN * stride;

    k_pre<<<320, 256, 0, stream>>>(t, W, Wf, af1, af2, Wb, ab1, ab2, Wg, ag1, ag2,
                                   u, s1, p, out, ccnt);
    k_scan<<<3 * NN / 4, 256, 0, stream>>>(Af, Ab, Ag, p, csr, cnt, s2, csc, ccnt, stride);
    k_zb<<<NN / 4, 256, 0, stream>>>(s1, s2, csr, cnt, stride, Zb);
    k_out<<<3 * NN / 16, 256, 0, stream>>>(u, s1, s2, Zb, csr, cnt, csc, ccnt, stride, out);
}

// Round 2
// 245.707 us; speedup vs baseline: 1.0356x; 1.0033x over previous
//
#include <hip/hip_runtime.h>

#define NN 4096
#define FF 128
#define EE 64

typedef unsigned short u16;
typedef unsigned long long u64;
typedef float vf4 __attribute__((ext_vector_type(4)));

__device__ __forceinline__ float lrelu(float x) { return x > 0.f ? x : 0.2f * x; }

// K0: fused pre-pass, two block kinds in ONE dispatch (they are independent):
//  blocks 0..63   : compute v6 (W_d @ a_d, redundantly per block into LDS) then
//                   s1/p for 64 nodes each. Blocks 0..15 also zero CSC counters.
//  blocks 64..319 : u = t@W.T (LDS-staged weight), out rows 0..63 as full lines.
__global__ __launch_bounds__(256)
void k_pre(const float* __restrict__ t, const float* __restrict__ weight,
           const float* __restrict__ Wf, const float* __restrict__ af1, const float* __restrict__ af2,
           const float* __restrict__ Wb, const float* __restrict__ ab1, const float* __restrict__ ab2,
           const float* __restrict__ Wg, const float* __restrict__ ag1, const float* __restrict__ ag2,
           float* __restrict__ u, float* __restrict__ s1, float* __restrict__ p,
           float* __restrict__ out, int* __restrict__ ccnt)
{
    __shared__ float ww[64 * 129];   // weight[e][q] at e*129+q  (129: bank-spread)
    __shared__ float tt[16 * 130];   // t[node][q] at node*130+q
    __shared__ float uacc[64 * 17];  // u[e][node] staging for transposed out write
    __shared__ float w6[6 * FF];     // v6 for the producer blocks
    int b = blockIdx.x, tid = threadIdx.x;

    if (b < 64) {
        // ---------- producer blocks: v6 -> s1/p ----------
        if (b < 16) ccnt[b * 256 + tid] = 0;
        const float* Ws[3]  = {Wf, Wb, Wg};
        const float* a1s[3] = {af1, ab1, ag1};
        const float* a2s[3] = {af2, ab2, ag2};
        for (int idx = tid; idx < 768; idx += 256) {
            int vi = idx >> 7, f = idx & 127, dd = vi >> 1;
            const float4* a4 = reinterpret_cast<const float4*>((vi & 1) ? a2s[dd] : a1s[dd]);
            const float4* W4 = reinterpret_cast<const float4*>(Ws[dd] + (size_t)f * EE);
            float s = 0.f;
            #pragma unroll
            for (int e4 = 0; e4 < 16; ++e4) {
                float4 wv = W4[e4], av = a4[e4];
                s += wv.x * av.x + wv.y * av.y + wv.z * av.z + wv.w * av.w;
            }
            w6[vi * FF + f] = s;
        }
        __syncthreads();
        int nb = b * 64;
        for (int idx = tid; idx < 384; idx += 256) {
            int n = idx & 63, vi = idx >> 6;      // vi uniform per wave -> w6 broadcast reads
            const float4* t4 = reinterpret_cast<const float4*>(t + (size_t)(nb + n) * FF);
            const float* wv = &w6[vi * FF];
            float s = 0.f;
            #pragma unroll 8
            for (int q4 = 0; q4 < 32; ++q4) {
                float4 v = t4[q4];
                s += v.x * wv[q4 * 4] + v.y * wv[q4 * 4 + 1]
                   + v.z * wv[q4 * 4 + 2] + v.w * wv[q4 * 4 + 3];
            }
            int dd = vi >> 1;
            if (vi & 1) p[dd * NN + nb + n] = s; else s1[dd * NN + nb + n] = s;
        }
        return;
    }

    // ---------- feat blocks: u + out rows 0..63 ----------
    int n0 = (b - 64) * 16;
    const float4* w4 = reinterpret_cast<const float4*>(weight);
    for (int i = tid; i < 2048; i += 256) {
        float4 v = w4[i];
        int fi = i * 4, e = fi >> 7, q = fi & 127;
        float* dst = &ww[e * 129 + q];
        dst[0] = v.x; dst[1] = v.y; dst[2] = v.z; dst[3] = v.w;
    }
    const float4* t4 = reinterpret_cast<const float4*>(t + (size_t)n0 * FF);
    for (int i = tid; i < 512; i += 256) {
        float4 v = t4[i];
        int fi = i * 4, nd = fi >> 7, q = fi & 127;
        float* dst = &tt[nd * 130 + q];
        dst[0] = v.x; dst[1] = v.y; dst[2] = v.z; dst[3] = v.w;
    }
    __syncthreads();
    int g = tid >> 6, lane = tid & 63;
    for (int k = 0; k < 4; ++k) {
        int nd = g * 4 + k;
        const float* trow = &tt[nd * 130];
        const float* wrow = &ww[lane * 129];
        float acc = 0.f;
        #pragma unroll 16
        for (int q = 0; q < 128; ++q) acc += wrow[q] * trow[q];
        u[(size_t)(n0 + nd) * EE + lane] = acc;
        uacc[lane * 17 + nd] = acc;
    }
    __syncthreads();
    int e = tid >> 2, io = (tid & 3) * 4;
    float* orow = out + (size_t)e * NN + n0 + io;
    orow[0] = uacc[e * 17 + io];
    orow[1] = uacc[e * 17 + io + 1];
    orow[2] = uacc[e * 17 + io + 2];
    orow[3] = uacc[e * 17 + io + 3];
}

// K1: streaming scan, NON-TEMPORAL adjacency loads. NEW (R2):
//  - persistent balanced grid: 1536 blocks (6/CU, fully resident, zero tail),
//    each wave owns exactly 2 CONSECUTIVE rows (d-major — reverts the R1
//    d%3 interleave, which cost locality/occupancy for nothing).
//  - explicit vf4 L[8] staging: ~8 outstanding loads per wave (VGPR<64 keeps
//    8 waves/SIMD) to fix the MLP shortfall (VGPR_Count=28 held only ~5).
__global__ __launch_bounds__(256, 8)
void k_scan(const float* __restrict__ Af, const float* __restrict__ Ab, const float* __restrict__ Ag,
            const float* __restrict__ p,
            u16* __restrict__ csr, int* __restrict__ cnt, float* __restrict__ s2,
            u16* __restrict__ csc, int* __restrict__ ccnt, int stride)
{
    int wid = threadIdx.x >> 6, lane = threadIdx.x & 63;
    int gw = blockIdx.x * 4 + wid;             // 0 .. 6143
    #pragma unroll 1
    for (int rr = 0; rr < 2; ++rr) {
        int gr = gw * 2 + rr;                  // 0 .. 12287 (d-major, consecutive)
        int d = gr >> 12, r = gr & (NN - 1);
        const float* A = d == 0 ? Af : (d == 1 ? Ab : Ag);
        const vf4* row4 = reinterpret_cast<const vf4*>(A + (size_t)r * NN);
        const float* pd = p + d * NN;

        u64 mask = 0ull;
        vf4 L[8];
        #pragma unroll
        for (int j = 0; j < 8; ++j) L[j] = __builtin_nontemporal_load(row4 + j * 64 + lane);
        #pragma unroll
        for (int j = 0; j < 8; ++j) {
            unsigned mm = (L[j].x != 0.f ? 1u : 0u) | (L[j].y != 0.f ? 2u : 0u) |
                          (L[j].z != 0.f ? 4u : 0u) | (L[j].w != 0.f ? 8u : 0u);
            mask |= ((u64)mm) << (j * 4);
        }
        #pragma unroll
        for (int j = 0; j < 8; ++j) L[j] = __builtin_nontemporal_load(row4 + (8 + j) * 64 + lane);
        #pragma unroll
        for (int j = 0; j < 8; ++j) {
            unsigned mm = (L[j].x != 0.f ? 1u : 0u) | (L[j].y != 0.f ? 2u : 0u) |
                          (L[j].z != 0.f ? 4u : 0u) | (L[j].w != 0.f ? 8u : 0u);
            mask |= ((u64)mm) << (32 + j * 4);
        }

        int lc = __popcll(mask);
        int sc = lc;
        for (int off = 1; off < 64; off <<= 1) {
            int o = __shfl_up(sc, off);
            if (lane >= off) sc += o;
        }
        int total = __shfl(sc, 63);
        int pos = sc - lc;
        u16* crow = csr + (size_t)gr * stride;
        float q = 0.f;
        u64 m = mask;
        while (m) {
            int bb = __ffsll(m) - 1;
            m &= m - 1;
            int col = ((bb >> 2) << 8) + (lane << 2) + (bb & 3);
            if (pos < stride) crow[pos] = (u16)col;
            pos++;
            q += pd[col];
            if (d == 1) {
                int cp = atomicAdd(&ccnt[col], 1);
                if (cp < stride) csc[(size_t)col * stride + cp] = (u16)r;
            }
        }
        for (int off = 32; off; off >>= 1) q += __shfl_xor(q, off);
        if (lane == 0) {
            cnt[gr] = total;
            s2[gr] = q / fmaxf((float)total, 1.f);
        }
    }
}

// K2: backward row denominators Zb[j] = sum_{col} exp(lrelu(s1b[j]+s2b[col]))
__global__ void k_zb(const float* __restrict__ s1, const float* __restrict__ s2,
                     const u16* __restrict__ csr, const int* __restrict__ cnt, int stride,
                     float* __restrict__ Zb)
{
    int tid = threadIdx.x, wave = tid >> 6, lane = tid & 63;
    int j = blockIdx.x * 4 + wave;
    int gr = NN + j;
    int nnz = min(cnt[gr], stride);
    const u16* crow = csr + (size_t)gr * stride;
    float s1j = s1[gr];
    const float* s2b = s2 + NN;
    float z = 0.f;
    if (lane < nnz)      z += __expf(lrelu(s1j + s2b[crow[lane]]));
    if (lane + 64 < nnz) z += __expf(lrelu(s1j + s2b[crow[lane + 64]]));
    for (int off = 32; off; off >>= 1) z += __shfl_xor(z, off);
    if (lane == 0) Zb[j] = z;
}

// K3: unified consumer, ILP-4 gather pipeline (4 independent 256-B u-row loads
// in flight per wave), results staged in LDS, written as FULL 64-B LINES.
__global__ __launch_bounds__(256)
void k_out(const float* __restrict__ u,
           const float* __restrict__ s1, const float* __restrict__ s2,
           const float* __restrict__ Zb,
           const u16* __restrict__ csr, const int* __restrict__ cnt,
           const u16* __restrict__ csc, const int* __restrict__ ccnt, int stride,
           float* __restrict__ out)
{
    __shared__ float oacc[16 * 66];
    int gr0 = blockIdx.x * 16;
    int d = gr0 >> 12, i0 = gr0 & (NN - 1);
    int wid = threadIdx.x >> 6, lane = threadIdx.x & 63;
    for (int k = 0; k < 4; ++k) {
        int lr = k * 4 + wid;
        int i = i0 + lr;
        int gr = gr0 + lr;
        int nnz;
        int c0v = 0, c1v = 0;
        float w0v = 0.f, w1v = 0.f;
        if (d == 1) {
            nnz = min(ccnt[i], stride);
            const u16* cc = csc + (size_t)i * stride;
            float s2i = s2[NN + i];
            if (lane < nnz)      { int j = cc[lane];      c0v = j; w0v = __expf(lrelu(s1[NN + j] + s2i)) / Zb[j]; }
            if (lane + 64 < nnz) { int j = cc[lane + 64]; c1v = j; w1v = __expf(lrelu(s1[NN + j] + s2i)) / Zb[j]; }
        } else {
            nnz = min(cnt[gr], stride);
            const u16* crow = csr + (size_t)gr * stride;
            float s1i = s1[gr];
            const float* s2d = s2 + d * NN;
            float z = 0.f;
            if (lane < nnz)      { int c = crow[lane];      c0v = c; w0v = __expf(lrelu(s1i + s2d[c])); z += w0v; }
            if (lane + 64 < nnz) { int c = crow[lane + 64]; c1v = c; w1v = __expf(lrelu(s1i + s2d[c])); z += w1v; }
            for (int off = 32; off; off >>= 1) z += __shfl_xor(z, off);
            float invz = z > 0.f ? 1.f / z : 0.f;
            w0v *= invz; w1v *= invz;
        }
        float a0 = 0.f, a1 = 0.f, a2 = 0.f, a3 = 0.f;
        int n0c = nnz < 64 ? nnz : 64;
        int kk = 0;
        for (; kk + 3 < n0c; kk += 4) {
            int ca = __shfl(c0v, kk),     cb = __shfl(c0v, kk + 1);
            int cc2 = __shfl(c0v, kk + 2), cd = __shfl(c0v, kk + 3);
            float wa = __shfl(w0v, kk),     wb = __shfl(w0v, kk + 1);
            float wc = __shfl(w0v, kk + 2), wd = __shfl(w0v, kk + 3);
            a0 += wa * u[(size_t)ca  * EE + lane];
            a1 += wb * u[(size_t)cb  * EE + lane];
            a2 += wc * u[(size_t)cc2 * EE + lane];
            a3 += wd * u[(size_t)cd  * EE + lane];
        }
        for (; kk < n0c; ++kk)
            a0 += __shfl(w0v, kk) * u[(size_t)__shfl(c0v, kk) * EE + lane];
        int n1c = nnz - 64;
        kk = 0;
        for (; kk + 3 < n1c; kk += 4) {
            int ca = __shfl(c1v, kk),     cb = __shfl(c1v, kk + 1);
            int cc2 = __shfl(c1v, kk + 2), cd = __shfl(c1v, kk + 3);
            float wa = __shfl(w1v, kk),     wb = __shfl(w1v, kk + 1);
            float wc = __shfl(w1v, kk + 2), wd = __shfl(w1v, kk + 3);
            a0 += wa * u[(size_t)ca  * EE + lane];
            a1 += wb * u[(size_t)cb  * EE + lane];
            a2 += wc * u[(size_t)cc2 * EE + lane];
            a3 += wd * u[(size_t)cd  * EE + lane];
        }
        for (; kk < n1c; ++kk)
            a0 += __shfl(w1v, kk) * u[(size_t)__shfl(c1v, kk) * EE + lane];
        oacc[lr * 66 + lane] = (a0 + a1) + (a2 + a3);
    }
    __syncthreads();
    int e = threadIdx.x >> 2, io = (threadIdx.x & 3) * 4;
    int base = 64 + (d << 6);
    float* orow = out + (size_t)(base + e) * NN + i0 + io;
    orow[0] = oacc[(io    ) * 66 + e];
    orow[1] = oacc[(io + 1) * 66 + e];
    orow[2] = oacc[(io + 2) * 66 + e];
    orow[3] = oacc[(io + 3) * 66 + e];
}

extern "C" void kernel_launch(void* const* d_in, const int* in_sizes, int n_in,
                              void* d_out, int out_size, void* d_ws, size_t ws_size,
                              hipStream_t stream)
{
    const float* t   = (const float*)d_in[0];
    const float* Ag  = (const float*)d_in[1];
    const float* Af  = (const float*)d_in[2];
    const float* Ab  = (const float*)d_in[3];
    const float* W   = (const float*)d_in[4];
    const float* Wf  = (const float*)d_in[5];
    const float* af1 = (const float*)d_in[6];
    const float* af2 = (const float*)d_in[7];
    const float* Wb  = (const float*)d_in[8];
    const float* ab1 = (const float*)d_in[9];
    const float* ab2 = (const float*)d_in[10];
    const float* Wg  = (const float*)d_in[11];
    const float* ag1 = (const float*)d_in[12];
    const float* ag2 = (const float*)d_in[13];
    float* out = (float*)d_out;

    float* ws = (float*)d_ws;
    float* v6  = ws;                              // 768 (unused slot kept for layout stability)
    float* s1  = v6 + 6 * FF;                     // 3N
    float* p   = s1 + 3 * NN;                     // 3N
    float* s2  = p + 3 * NN;                      // 3N
    float* Zb  = s2 + 3 * NN;                     // N
    float* u   = Zb + NN;                         // N*E
    int*   cnt  = (int*)(u + (size_t)NN * EE);    // 3N
    int*   ccnt = cnt + 3 * NN;                   // N
    u16*   csr  = (u16*)(ccnt + NN);              // 3N*stride
    // csc follows csr: N*stride

    size_t base_bytes = ((char*)csr) - ((char*)d_ws);
    int stride = 128;
    if (base_bytes + (size_t)4 * NN * 128 * 2 > ws_size) stride = 96;
    if (base_bytes + (size_t)4 * NN * 96 * 2 > ws_size)  stride = 64;
    u16* csc = csr + (size_t)3 * NN * stride;

    k_pre<<<320, 256, 0, stream>>>(t, W, Wf, af1, af2, Wb, ab1, ab2, Wg, ag1, ag2,
                                   u, s1, p, out, ccnt);
    k_scan<<<1536, 256, 0, stream>>>(Af, Ab, Ag, p, csr, cnt, s2, csc, ccnt, stride);
    k_zb<<<NN / 4, 256, 0, stream>>>(s1, s2, csr, cnt, stride, Zb);
    k_out<<<3 * NN / 16, 256, 0, stream>>>(u, s1, s2, Zb, csr, cnt, csc, ccnt, stride, out);
}